// Round 1
// baseline (2018.396 us; speedup 1.0000x reference)
//
#include <hip/hip_runtime.h>
#include <stdint.h>

#define B_ 32
#define S_ 512
#define D_ 768
#define H_ 12
#define DH_ 64
#define SPLIT_ 2
#define ROWS_ (S_ / SPLIT_)  // 256 rows per block

// ---- dynamic LDS layout (bytes) ----
// Ks : u16[512][66]  K row-major bf16, pitch 66 (33 words, odd -> conflict-free)
// Vt : u16[64][514]  V transposed bf16, pitch 514 (257 words, odd -> conflict-free)
// Wql: u16[64][66]   Wq bf16 [e][d]
// xs : f32[64][68]   x staging (phase 1); first 8KB reused as pbuf (phase 2)
#define KS_OFF   0
#define KS_PITCH 66
#define VT_OFF   67584
#define VT_PITCH 514
#define WQ_OFF   133376
#define WQ_PITCH 66
#define XS_OFF   141824
#define XS_PITCH 68
#define SMEM_BYTES 159232  // <= 163840

__device__ __forceinline__ float bflo(uint32_t u) {
  return __builtin_bit_cast(float, u << 16);
}
__device__ __forceinline__ float bfhi(uint32_t u) {
  return __builtin_bit_cast(float, u & 0xffff0000u);
}
__device__ __forceinline__ unsigned short f2bf(float f) {
  uint32_t u = __builtin_bit_cast(uint32_t, f);
  uint32_t r = (u + 0x7fffu + ((u >> 16) & 1u)) >> 16;  // RNE
  return (unsigned short)r;
}

extern "C" __global__ void __launch_bounds__(256, 1)
mhsa_kernel(const float* __restrict__ seq,
            const float* __restrict__ Wq, const float* __restrict__ Wk,
            const float* __restrict__ Wv,
            const float* __restrict__ bq, const float* __restrict__ bk,
            const float* __restrict__ bv,
            float* __restrict__ out)
{
  extern __shared__ char smem[];
  unsigned short* Ks  = (unsigned short*)(smem + KS_OFF);
  unsigned short* Vt  = (unsigned short*)(smem + VT_OFF);
  unsigned short* Wql = (unsigned short*)(smem + WQ_OFF);
  float*          xs  = (float*)(smem + XS_OFF);
  uint32_t* Ks32 = (uint32_t*)Ks;
  uint32_t* Vt32 = (uint32_t*)Vt;
  uint32_t* Wq32 = (uint32_t*)Wql;
  float*    pbuf = xs;  // phase-2 reuse (4 waves x 512 f32 = 8KB <= 17408)

  const int tid  = threadIdx.x;
  const int lane = tid & 63;
  const int wid  = tid >> 6;
  const int bh   = blockIdx.x;
  const int b    = bh / H_;
  const int h    = bh - b * H_;
  const int hv   = blockIdx.y;  // which half of the q rows

  const float bq_r = bq[h * DH_ + lane];

  // ---- stage Wq as bf16 [e][d] pitch 66 ----
  for (int idx = tid; idx < DH_ * DH_; idx += 256) {
    int e = idx >> 6, d = idx & 63;
    Wql[e * WQ_PITCH + d] = f2bf(Wq[(h * DH_ + e) * DH_ + d]);
  }

  // ---- phase 1: K,V projections into LDS (bf16) ----
  const float4* Wk4 = (const float4*)(Wk + h * DH_ * DH_);
  const float4* Wv4 = (const float4*)(Wv + h * DH_ * DH_);
  const float4* x4  = (const float4*)xs;
  for (int c = 0; c < 8; ++c) {
    __syncthreads();  // protect xs reuse across chunks
    #pragma unroll
    for (int i = 0; i < 16; ++i) {  // 64*64 floats / 256 threads
      int idx = tid + i * 256;
      int tr = idx >> 6, d = idx & 63;
      xs[tr * XS_PITCH + d] =
          seq[((size_t)(b * S_ + c * 64 + tr)) * D_ + h * DH_ + d];
    }
    __syncthreads();
    const int t = c * 64 + lane;  // each lane owns one t-row of the chunk
    for (int p = 0; p < 16; ++p) {
      const int e = __builtin_amdgcn_readfirstlane(wid + 4 * p);  // wave-uniform
      float aK = 0.f, aV = 0.f;
      #pragma unroll
      for (int d4 = 0; d4 < 16; ++d4) {
        float4 xv = x4[lane * 17 + d4];   // pitch 68 f32 = 17 float4
        float4 k4 = Wk4[e * 16 + d4];     // uniform -> s_load
        float4 v4 = Wv4[e * 16 + d4];
        aK += xv.x * k4.x; aK += xv.y * k4.y; aK += xv.z * k4.z; aK += xv.w * k4.w;
        aV += xv.x * v4.x; aV += xv.y * v4.y; aV += xv.z * v4.z; aV += xv.w * v4.w;
      }
      aK += bk[h * DH_ + e];
      aV += bv[h * DH_ + e];
      Ks[t * KS_PITCH + e] = f2bf(aK);   // lanes stride 33 words: conflict-free
      Vt[e * VT_PITCH + t] = f2bf(aV);   // lanes consecutive u16: conflict-free
    }
  }
  __syncthreads();

  // ---- phase 2: per-wave rows, no block barriers ----
  const uint32_t* Wqr  = Wq32 + lane * 33;   // Wq row e=lane (bf16 pairs)
  const uint32_t* vrow = Vt32 + lane * 257;  // V^T row e=lane
  float* pb = pbuf + wid * S_;
  const float4* pb4 = (const float4*)pb;

  for (int rr = wid; rr < ROWS_; rr += 4) {
    const int r = hv * ROWS_ + __builtin_amdgcn_readfirstlane(rr);
    // q[e], e = lane (fp32 acc, bf16 weights)
    const float4* xr4 = (const float4*)(seq + ((size_t)(b * S_ + r)) * D_ + h * DH_);
    float acc = bq_r;
    #pragma unroll
    for (int d4 = 0; d4 < 16; ++d4) {
      float4 xv = xr4[d4];
      uint32_t w01 = Wqr[d4 * 2];
      uint32_t w23 = Wqr[d4 * 2 + 1];
      acc += xv.x * bflo(w01); acc += xv.y * bfhi(w01);
      acc += xv.z * bflo(w23); acc += xv.w * bfhi(w23);
    }
    // scores: lane owns t = lane + 64j
    float sc[8];
    #pragma unroll
    for (int j = 0; j < 8; ++j) sc[j] = 0.f;
    const int qbits = __builtin_bit_cast(int, acc);
    #pragma unroll 8
    for (int e2 = 0; e2 < 32; ++e2) {
      float q0 = __builtin_bit_cast(float, __builtin_amdgcn_readlane(qbits, 2 * e2));
      float q1 = __builtin_bit_cast(float, __builtin_amdgcn_readlane(qbits, 2 * e2 + 1));
      #pragma unroll
      for (int j = 0; j < 8; ++j) {
        uint32_t kp = Ks32[(lane + 64 * j) * 33 + e2];
        sc[j] += q0 * bflo(kp);
        sc[j] += q1 * bfhi(kp);
      }
    }
    // wave softmax (max-sub), denominators over all 512 t
    float m = sc[0];
    #pragma unroll
    for (int j = 1; j < 8; ++j) m = fmaxf(m, sc[j]);
    #pragma unroll
    for (int i = 32; i >= 1; i >>= 1) m = fmaxf(m, __shfl_xor(m, i, 64));
    float l = 0.f;
    float pr[8];
    #pragma unroll
    for (int j = 0; j < 8; ++j) { pr[j] = __expf(sc[j] - m); l += pr[j]; }
    #pragma unroll
    for (int i = 32; i >= 1; i >>= 1) l += __shfl_xor(l, i, 64);
    const float inv = 1.0f / l;
    // publish p to wave-private pbuf, then PV from V^T
    #pragma unroll
    for (int j = 0; j < 8; ++j) pb[lane + 64 * j] = pr[j];
    asm volatile("s_waitcnt lgkmcnt(0)" ::: "memory");
    float oacc = 0.f;
    #pragma unroll 8
    for (int tc = 0; tc < 128; ++tc) {
      float4 p4 = pb4[tc];                 // uniform b128 broadcast
      uint32_t v01 = vrow[tc * 2];
      uint32_t v23 = vrow[tc * 2 + 1];
      oacc += p4.x * bflo(v01); oacc += p4.y * bfhi(v01);
      oacc += p4.z * bflo(v23); oacc += p4.w * bfhi(v23);
    }
    out[((size_t)(b * S_ + r)) * D_ + h * DH_ + lane] = oacc * inv;
  }
}

extern "C" void kernel_launch(void* const* d_in, const int* in_sizes, int n_in,
                              void* d_out, int out_size, void* d_ws, size_t ws_size,
                              hipStream_t stream) {
  const float* seq = (const float*)d_in[0];
  const float* Wq  = (const float*)d_in[1];
  const float* Wk  = (const float*)d_in[2];
  const float* Wv  = (const float*)d_in[3];
  const float* bq  = (const float*)d_in[4];
  const float* bk  = (const float*)d_in[5];
  const float* bv  = (const float*)d_in[6];
  float* outp = (float*)d_out;

  hipFuncSetAttribute((const void*)mhsa_kernel,
                      hipFuncAttributeMaxDynamicSharedMemorySize, SMEM_BYTES);
  dim3 grid(B_ * H_, SPLIT_);
  mhsa_kernel<<<grid, 256, SMEM_BYTES, stream>>>(seq, Wq, Wk, Wv, bq, bk, bv, outp);
}

// Round 2
// 106.241 us; speedup vs baseline: 18.9984x; 18.9984x over previous
//
#include <hip/hip_runtime.h>
#include <stdint.h>

#define B_ 32
#define S_ 512
#define D_ 768
#define H_ 12
#define DH_ 64

typedef __attribute__((ext_vector_type(8))) short bf16x8;
typedef __attribute__((ext_vector_type(4))) float f32x4;
typedef __attribute__((ext_vector_type(4))) short short4v;

// ---- LDS layout (u16 units) ----
// Ws : [3][64][64] bf16 (Wq,Wk,Wv)           @ 0      (24576 B)
// xs : [128][68]   bf16 x-chunk              @ 12288  (17408 B)
// Kc : [128][68]   bf16 K-chunk (row-major)  @ 20992  (17408 B)
// Vt : [64][132]   bf16 V^T-chunk            @ 29696  (16896 B)
#define XPITCH 68
#define VPITCH 132
#define WS_U 0
#define XS_U 12288
#define KC_U 20992
#define VT_U 29696
#define SMEM_BYTES 76288

__device__ __forceinline__ unsigned short f2bf(float f) {
  uint32_t u = __builtin_bit_cast(uint32_t, f);
  uint32_t r = (u + 0x7fffu + ((u >> 16) & 1u)) >> 16;  // RNE
  return (unsigned short)r;
}

__device__ __forceinline__ bf16x8 ldfrag(const unsigned short* p) {
  // reads cols +0..3 and +16..19 of a row-major LDS row (two b64s)
  short4v a = *(const short4v*)p;
  short4v b = *(const short4v*)(p + 16);
  bf16x8 f;
  f[0] = a[0]; f[1] = a[1]; f[2] = a[2]; f[3] = a[3];
  f[4] = b[0]; f[5] = b[1]; f[6] = b[2]; f[7] = b[3];
  return f;
}

#define MFMA(a, b, c) __builtin_amdgcn_mfma_f32_16x16x32_bf16((a), (b), (c), 0, 0, 0)

extern "C" __global__ void __launch_bounds__(512, 2)
mhsa_mfma(const float* __restrict__ seq, const float* __restrict__ Wq,
          const float* __restrict__ Wk, const float* __restrict__ Wv,
          const float* __restrict__ bq, const float* __restrict__ bk,
          const float* __restrict__ bv, float* __restrict__ out)
{
  extern __shared__ unsigned short lds[];
  unsigned short* Ws = lds + WS_U;
  unsigned short* xs = lds + XS_U;
  unsigned short* Kc = lds + KC_U;
  unsigned short* Vt = lds + VT_U;

  const int tid = threadIdx.x;
  const int lane = tid & 63;
  const int w = tid >> 6;       // wave 0..7
  const int g = lane >> 4;      // lane quad-group 0..3
  const int r16 = lane & 15;
  const int cb = g * 4;         // fragment column base
  const int bh = blockIdx.x;
  const int b = bh / H_;
  const int h = bh - b * H_;
  const int r0 = blockIdx.y * 256;  // this block's q-row base

  const float* seqh = seq + (size_t)b * (S_ * D_) + h * DH_;

  // ---- stage W fp32 -> bf16 LDS ----
  #pragma unroll
  for (int i = 0; i < 24; ++i) {
    int idx = tid + i * 512;
    const float* src = (idx < 4096) ? (Wq + h * 4096 + idx)
                     : (idx < 8192) ? (Wk + h * 4096 + (idx - 4096))
                                    : (Wv + h * 4096 + (idx - 8192));
    Ws[idx] = f2bf(*src);
  }
  __syncthreads();

  // ---- persistent W fragments ----
  bf16x8 wkB[4][2];  // B-frags for K-proj: elem j = Wk[16*e4+(l&15)][myk+32ec]
  #pragma unroll
  for (int e4 = 0; e4 < 4; ++e4)
    #pragma unroll
    for (int ec = 0; ec < 2; ++ec)
      wkB[e4][ec] = ldfrag(Ws + 4096 + (16 * e4 + r16) * 64 + cb + 32 * ec);
  const int ev = w & 3;   // V^T e-tile owned by this wave
  const int th = w >> 2;  // V^T t-half
  bf16x8 wvA[2];          // A-frags for V^T-proj
  #pragma unroll
  for (int ec = 0; ec < 2; ++ec)
    wvA[ec] = ldfrag(Ws + 8192 + (16 * ev + r16) * 64 + cb + 32 * ec);

  float bk_l[4], bv_l[4];
  #pragma unroll
  for (int e4 = 0; e4 < 4; ++e4) bk_l[e4] = bk[h * 64 + 16 * e4 + r16];
  #pragma unroll
  for (int rr = 0; rr < 4; ++rr) bv_l[rr] = bv[h * 64 + 16 * ev + 4 * g + rr];

  // ---- pre-phase: Q^T via MFMA -> qB register fragments ----
  bf16x8 qB[2][2];  // [m-tile][e-chunk]
  for (int cq = 0; cq < 2; ++cq) {
    __syncthreads();
    #pragma unroll
    for (int i = 0; i < 4; ++i) {
      int e = tid + i * 512;
      int row = e >> 4, c4 = (e & 15) * 4;
      const float4 xv = *(const float4*)(seqh + (size_t)(r0 + cq * 128 + row) * D_ + c4);
      short4v s = {(short)f2bf(xv.x), (short)f2bf(xv.y), (short)f2bf(xv.z), (short)f2bf(xv.w)};
      *(short4v*)(xs + row * XPITCH + c4) = s;
    }
    __syncthreads();
    if ((w >> 2) == cq) {
      const int lr = 32 * (w & 3);  // wave's rows within this 128-chunk
      #pragma unroll
      for (int mt = 0; mt < 2; ++mt) {
        bf16x8 xB[2];
        #pragma unroll
        for (int ec = 0; ec < 2; ++ec)
          xB[ec] = ldfrag(xs + (lr + 16 * mt + r16) * XPITCH + cb + 32 * ec);
        f32x4 qt[4];
        #pragma unroll
        for (int e4 = 0; e4 < 4; ++e4) {
          f32x4 acc = {0.f, 0.f, 0.f, 0.f};
          #pragma unroll
          for (int ec = 0; ec < 2; ++ec)
            acc = MFMA(ldfrag(Ws + (16 * e4 + r16) * 64 + cb + 32 * ec), xB[ec], acc);
          qt[e4] = acc;
        }
        #pragma unroll
        for (int ec2 = 0; ec2 < 2; ++ec2) {
          bf16x8 f;
          #pragma unroll
          for (int j = 0; j < 8; ++j) {
            int e4 = 2 * ec2 + (j >> 2), rr = j & 3;
            f[j] = (short)f2bf(qt[e4][rr] + bq[h * 64 + 16 * e4 + 4 * g + rr]);
          }
          qB[mt][ec2] = f;
        }
      }
    }
  }

  // ---- main flash loop over 4 t-chunks of 128 ----
  f32x4 O[2][4];
  #pragma unroll
  for (int mt = 0; mt < 2; ++mt)
    #pragma unroll
    for (int e4 = 0; e4 < 4; ++e4) O[mt][e4] = {0.f, 0.f, 0.f, 0.f};
  float m_st[2] = {-1e30f, -1e30f}, l_st[2] = {0.f, 0.f};
  const int m0w = w * 32;

  for (int c = 0; c < 4; ++c) {
    __syncthreads();  // prev chunk's consumers done
    #pragma unroll
    for (int i = 0; i < 4; ++i) {
      int e = tid + i * 512;
      int row = e >> 4, c4 = (e & 15) * 4;
      const float4 xv = *(const float4*)(seqh + (size_t)(c * 128 + row) * D_ + c4);
      short4v s = {(short)f2bf(xv.x), (short)f2bf(xv.y), (short)f2bf(xv.z), (short)f2bf(xv.w)};
      *(short4v*)(xs + row * XPITCH + c4) = s;
    }
    __syncthreads();

    // K-proj: wave w owns t-tile w
    {
      bf16x8 aX[2];
      #pragma unroll
      for (int ec = 0; ec < 2; ++ec)
        aX[ec] = ldfrag(xs + (w * 16 + r16) * XPITCH + cb + 32 * ec);
      #pragma unroll
      for (int e4 = 0; e4 < 4; ++e4) {
        f32x4 acc = {0.f, 0.f, 0.f, 0.f};
        #pragma unroll
        for (int ec = 0; ec < 2; ++ec) acc = MFMA(aX[ec], wkB[e4][ec], acc);
        #pragma unroll
        for (int rr = 0; rr < 4; ++rr)
          Kc[(w * 16 + 4 * g + rr) * XPITCH + 16 * e4 + r16] = f2bf(acc[rr] + bk_l[e4]);
      }
    }
    // V^T-proj: wave w owns e-tile ev, t-tiles th*4..th*4+3
    #pragma unroll
    for (int ttl = 0; ttl < 4; ++ttl) {
      int tt = th * 4 + ttl;
      bf16x8 xB[2];
      #pragma unroll
      for (int ec = 0; ec < 2; ++ec)
        xB[ec] = ldfrag(xs + (tt * 16 + r16) * XPITCH + cb + 32 * ec);
      f32x4 acc = {0.f, 0.f, 0.f, 0.f};
      #pragma unroll
      for (int ec = 0; ec < 2; ++ec) acc = MFMA(wvA[ec], xB[ec], acc);
      #pragma unroll
      for (int rr = 0; rr < 4; ++rr)
        Vt[(16 * ev + 4 * g + rr) * VPITCH + tt * 16 + r16] = f2bf(acc[rr] + bv_l[rr]);
    }
    __syncthreads();

    // S^T + online softmax + PV
    bf16x8 pA[4][2];
    #pragma unroll
    for (int mt = 0; mt < 2; ++mt) {
      f32x4 st[8];
      #pragma unroll
      for (int tt = 0; tt < 8; ++tt) {
        bf16x8 aK[2];
        #pragma unroll
        for (int ec = 0; ec < 2; ++ec)
          aK[ec] = ldfrag(Kc + (tt * 16 + r16) * XPITCH + cb + 32 * ec);
        f32x4 acc = {0.f, 0.f, 0.f, 0.f};
        #pragma unroll
        for (int ec = 0; ec < 2; ++ec) acc = MFMA(aK[ec], qB[mt][ec], acc);
        st[tt] = acc;
      }
      float mx = st[0][0];
      #pragma unroll
      for (int tt = 0; tt < 8; ++tt)
        #pragma unroll
        for (int rr = 0; rr < 4; ++rr) mx = fmaxf(mx, st[tt][rr]);
      mx = fmaxf(mx, __shfl_xor(mx, 16, 64));
      mx = fmaxf(mx, __shfl_xor(mx, 32, 64));
      float mn = fmaxf(m_st[mt], mx);
      float al = __expf(m_st[mt] - mn);
      m_st[mt] = mn;
      float sum = 0.f;
      #pragma unroll
      for (int tt = 0; tt < 8; ++tt)
        #pragma unroll
        for (int rr = 0; rr < 4; ++rr) {
          float pv = __expf(st[tt][rr] - mn);
          st[tt][rr] = pv;
          sum += pv;
        }
      sum += __shfl_xor(sum, 16, 64);
      sum += __shfl_xor(sum, 32, 64);
      l_st[mt] = l_st[mt] * al + sum;
      float af[4];
      #pragma unroll
      for (int rr = 0; rr < 4; ++rr) af[rr] = __shfl(al, 4 * g + rr, 64);
      #pragma unroll
      for (int e4 = 0; e4 < 4; ++e4)
        #pragma unroll
        for (int rr = 0; rr < 4; ++rr) O[mt][e4][rr] *= af[rr];
      #pragma unroll
      for (int u = 0; u < 4; ++u) {
        bf16x8 f;
        #pragma unroll
        for (int j = 0; j < 8; ++j) f[j] = (short)f2bf(st[2 * u + (j >> 2)][j & 3]);
        pA[u][mt] = f;
      }
    }
    #pragma unroll
    for (int u = 0; u < 4; ++u) {
      bf16x8 vB[4];
      #pragma unroll
      for (int e4 = 0; e4 < 4; ++e4)
        vB[e4] = ldfrag(Vt + (16 * e4 + r16) * VPITCH + 32 * u + cb);
      #pragma unroll
      for (int mt = 0; mt < 2; ++mt)
        #pragma unroll
        for (int e4 = 0; e4 < 4; ++e4)
          O[mt][e4] = MFMA(pA[u][mt], vB[e4], O[mt][e4]);
    }
  }

  // ---- epilogue: normalize + store ----
  #pragma unroll
  for (int mt = 0; mt < 2; ++mt) {
    float inv[4];
    #pragma unroll
    for (int rr = 0; rr < 4; ++rr) inv[rr] = 1.0f / __shfl(l_st[mt], 4 * g + rr, 64);
    #pragma unroll
    for (int e4 = 0; e4 < 4; ++e4)
      #pragma unroll
      for (int rr = 0; rr < 4; ++rr)
        out[(size_t)(b * S_ + r0 + m0w + 16 * mt + 4 * g + rr) * D_ + h * DH_ + 16 * e4 + r16] =
            O[mt][e4][rr] * inv[rr];
  }
}

extern "C" void kernel_launch(void* const* d_in, const int* in_sizes, int n_in,
                              void* d_out, int out_size, void* d_ws, size_t ws_size,
                              hipStream_t stream) {
  const float* seq = (const float*)d_in[0];
  const float* Wq  = (const float*)d_in[1];
  const float* Wk  = (const float*)d_in[2];
  const float* Wv  = (const float*)d_in[3];
  const float* bq  = (const float*)d_in[4];
  const float* bk  = (const float*)d_in[5];
  const float* bv  = (const float*)d_in[6];
  float* outp = (float*)d_out;

  hipFuncSetAttribute((const void*)mhsa_mfma,
                      hipFuncAttributeMaxDynamicSharedMemorySize, SMEM_BYTES);
  dim3 grid(B_ * H_, 2);
  mhsa_mfma<<<grid, 512, SMEM_BYTES, stream>>>(seq, Wq, Wk, Wv, bq, bk, bv, outp);
}

// Round 5
// 83.083 us; speedup vs baseline: 24.2937x; 1.2787x over previous
//
#include <hip/hip_runtime.h>
#include <stdint.h>

#define B_ 32
#define S_ 512
#define D_ 768
#define H_ 12
#define DH_ 64

typedef __attribute__((ext_vector_type(8))) short bf16x8;
typedef __attribute__((ext_vector_type(4))) float f32x4;
typedef __attribute__((ext_vector_type(4))) short short4v;

// ---- LDS layout (u16 units), pitch 72/136 => conflict-free b128 fragment reads
// (slot index == (9*row + g) mod 8 == (row+g) mod 8 -> consecutive 8 lanes
//  cover 8 distinct bank-quads).
// Ws : [192][72] bf16  Wq rows 0-63, Wk 64-127, Wv 128-191   @ 0
// xs : [128][72] bf16  x chunk                               @ 13824
// Kc : [128][72] bf16  K chunk, e-cols sigma-permuted        @ 23040
// Vt : [64][136] bf16  V^T chunk, t-cols sigma-permuted      @ 32256
#define WP 72
#define VP 136
#define WS_U 0
#define XS_U 13824
#define KC_U 23040
#define VT_U 32256
#define SMEM_BYTES 81920  // 40960 u16, 2 blocks/CU

__device__ __forceinline__ unsigned short f2bf(float f) {
  uint32_t u = __builtin_bit_cast(uint32_t, f);
  return (unsigned short)((u + 0x7fffu + ((u >> 16) & 1u)) >> 16);  // RNE
}

// sigma: value index v = 16*tile + r16  ->  stored col so that a contiguous
// 8-elem read at col8 = 32c + 8g yields k-order 32c + 16*(j>>2) + 4g + (j&3)
// (the C-layout order of register fragments qB/pA).
__device__ __forceinline__ int sigma(int tile, int r16) {
  return 32 * (tile >> 1) + 8 * (r16 >> 2) + 4 * (tile & 1) + (r16 & 3);
}

__device__ __forceinline__ bf16x8 ldfrag8(const unsigned short* p) {
  return *(const bf16x8*)p;  // single ds_read_b128
}

#define MFMA(a, b, c) __builtin_amdgcn_mfma_f32_16x16x32_bf16((a), (b), (c), 0, 0, 0)

extern "C" __global__ void __launch_bounds__(512, 2)
mhsa_mfma(const float* __restrict__ seq, const float* __restrict__ Wq,
          const float* __restrict__ Wk, const float* __restrict__ Wv,
          const float* __restrict__ bq, const float* __restrict__ bk,
          const float* __restrict__ bv, float* __restrict__ out)
{
  extern __shared__ unsigned short lds[];
  unsigned short* Ws = lds + WS_U;
  unsigned short* xs = lds + XS_U;
  unsigned short* Kc = lds + KC_U;
  unsigned short* Vt = lds + VT_U;

  const int tid = threadIdx.x;
  const int lane = tid & 63;
  const int w = tid >> 6;       // wave 0..7
  const int g = lane >> 4;      // lane quad-group 0..3
  const int r16 = lane & 15;
  const int bh = blockIdx.x;
  const int b = bh / H_;
  const int h = bh - b * H_;
  const int r0 = blockIdx.y * 256;  // this block's q-row base
  const int cb8 = 8 * g;            // contiguous fragment column base

  const float* seqh = seq + (size_t)b * (S_ * D_) + h * DH_;

  // ---- stage W fp32 -> bf16 LDS (rows padded to pitch 72) ----
  #pragma unroll
  for (int i = 0; i < 24; ++i) {
    int idx = tid + i * 512;
    int row = idx >> 6, col = idx & 63;
    const float* src = (idx < 4096) ? (Wq + h * 4096 + idx)
                     : (idx < 8192) ? (Wk + h * 4096 + (idx - 4096))
                                    : (Wv + h * 4096 + (idx - 8192));
    Ws[row * WP + col] = f2bf(*src);
  }
  __syncthreads();

  // ---- persistent W fragments (contiguous-8 k-order; consistent both sides) ----
  bf16x8 wkB[4][2];
  #pragma unroll
  for (int e4 = 0; e4 < 4; ++e4)
    #pragma unroll
    for (int ec = 0; ec < 2; ++ec)
      wkB[e4][ec] = ldfrag8(Ws + (64 + 16 * e4 + r16) * WP + 32 * ec + cb8);
  const int ev = w & 3;   // V^T e-tile owned by this wave
  const int th = w >> 2;  // V^T t-half
  bf16x8 wvA[2];
  #pragma unroll
  for (int ec = 0; ec < 2; ++ec)
    wvA[ec] = ldfrag8(Ws + (128 + 16 * ev + r16) * WP + 32 * ec + cb8);

  float bk_l[4], bv_l[4];
  #pragma unroll
  for (int e4 = 0; e4 < 4; ++e4) bk_l[e4] = bk[h * 64 + 16 * e4 + r16];
  #pragma unroll
  for (int rr = 0; rr < 4; ++rr) bv_l[rr] = bv[h * 64 + 16 * ev + 4 * g + rr];

  // ---- pre-phase: Q^T via MFMA -> qB register fragments ----
  bf16x8 qB[2][2];  // [m-tile][e-chunk]; elem j: e = 32ec2+16(j>>2)+4g+(j&3)
  for (int cq = 0; cq < 2; ++cq) {
    __syncthreads();
    #pragma unroll
    for (int i = 0; i < 4; ++i) {
      int idx = tid + i * 512;
      int row = idx >> 4, c4 = (idx & 15) << 2;
      const float4 xv = *(const float4*)(seqh + (size_t)(r0 + cq * 128 + row) * D_ + c4);
      short4v s = {(short)f2bf(xv.x), (short)f2bf(xv.y), (short)f2bf(xv.z), (short)f2bf(xv.w)};
      *(short4v*)(xs + row * WP + c4) = s;
    }
    __syncthreads();
    if (th == cq) {
      const int lr = 32 * ev;  // wave's rows within this 128-chunk
      #pragma unroll
      for (int mt = 0; mt < 2; ++mt) {
        bf16x8 xB[2];
        #pragma unroll
        for (int ec = 0; ec < 2; ++ec)
          xB[ec] = ldfrag8(xs + (lr + 16 * mt + r16) * WP + 32 * ec + cb8);
        f32x4 qt[4];
        #pragma unroll
        for (int e4 = 0; e4 < 4; ++e4) {
          f32x4 acc = {0.f, 0.f, 0.f, 0.f};
          #pragma unroll
          for (int ec = 0; ec < 2; ++ec)
            acc = MFMA(ldfrag8(Ws + (16 * e4 + r16) * WP + 32 * ec + cb8), xB[ec], acc);
          qt[e4] = acc;
        }
        #pragma unroll
        for (int ec2 = 0; ec2 < 2; ++ec2) {
          bf16x8 f;
          #pragma unroll
          for (int j = 0; j < 8; ++j) {
            int e4 = 2 * ec2 + (j >> 2), rr = j & 3;
            f[j] = (short)f2bf(qt[e4][rr] + bq[h * 64 + 16 * e4 + 4 * g + rr]);
          }
          qB[mt][ec2] = f;
        }
      }
    }
  }

  // ---- main flash loop over 4 t-chunks of 128 ----
  f32x4 O[2][4];
  #pragma unroll
  for (int mt = 0; mt < 2; ++mt)
    #pragma unroll
    for (int e4 = 0; e4 < 4; ++e4) O[mt][e4] = {0.f, 0.f, 0.f, 0.f};
  float m_st[2] = {-1e30f, -1e30f}, l_st[2] = {0.f, 0.f};
  const int m0w = w * 32;

  for (int c = 0; c < 4; ++c) {
    __syncthreads();  // prev chunk's consumers done
    #pragma unroll
    for (int i = 0; i < 4; ++i) {
      int idx = tid + i * 512;
      int row = idx >> 4, c4 = (idx & 15) << 2;
      const float4 xv = *(const float4*)(seqh + (size_t)(c * 128 + row) * D_ + c4);
      short4v s = {(short)f2bf(xv.x), (short)f2bf(xv.y), (short)f2bf(xv.z), (short)f2bf(xv.w)};
      *(short4v*)(xs + row * WP + c4) = s;
    }
    __syncthreads();

    // K-proj: wave w owns t-tile w; store e-cols sigma-permuted
    {
      bf16x8 aX[2];
      #pragma unroll
      for (int ec = 0; ec < 2; ++ec)
        aX[ec] = ldfrag8(xs + (w * 16 + r16) * WP + 32 * ec + cb8);
      #pragma unroll
      for (int e4 = 0; e4 < 4; ++e4) {
        f32x4 acc = {0.f, 0.f, 0.f, 0.f};
        #pragma unroll
        for (int ec = 0; ec < 2; ++ec) acc = MFMA(aX[ec], wkB[e4][ec], acc);
        const float bkv = bk_l[e4];
        const int rb = w * 16 + 4 * g;
        const int cs = sigma(e4, r16);
        Kc[(rb + 0) * WP + cs] = f2bf(acc[0] + bkv);
        Kc[(rb + 1) * WP + cs] = f2bf(acc[1] + bkv);
        Kc[(rb + 2) * WP + cs] = f2bf(acc[2] + bkv);
        Kc[(rb + 3) * WP + cs] = f2bf(acc[3] + bkv);
      }
    }
    // V^T-proj: wave w owns e-tile ev, t-tiles th*4..th*4+3; t-cols sigma-permuted
    #pragma unroll
    for (int ttl = 0; ttl < 4; ++ttl) {
      int tt = th * 4 + ttl;
      bf16x8 xB[2];
      #pragma unroll
      for (int ec = 0; ec < 2; ++ec)
        xB[ec] = ldfrag8(xs + (tt * 16 + r16) * WP + 32 * ec + cb8);
      f32x4 acc = {0.f, 0.f, 0.f, 0.f};
      #pragma unroll
      for (int ec = 0; ec < 2; ++ec) acc = MFMA(wvA[ec], xB[ec], acc);
      const int rb = 16 * ev + 4 * g;
      const int cs = sigma(tt, r16);
      Vt[(rb + 0) * VP + cs] = f2bf(acc[0] + bv_l[0]);
      Vt[(rb + 1) * VP + cs] = f2bf(acc[1] + bv_l[1]);
      Vt[(rb + 2) * VP + cs] = f2bf(acc[2] + bv_l[2]);
      Vt[(rb + 3) * VP + cs] = f2bf(acc[3] + bv_l[3]);
    }
    __syncthreads();

    // S^T + online softmax + PV
    bf16x8 pA[4][2];
    #pragma unroll
    for (int mt = 0; mt < 2; ++mt) {
      f32x4 st[8];
      #pragma unroll
      for (int tt = 0; tt < 8; ++tt) {
        bf16x8 aK[2];
        #pragma unroll
        for (int ec = 0; ec < 2; ++ec)
          aK[ec] = ldfrag8(Kc + (tt * 16 + r16) * WP + 32 * ec + cb8);
        f32x4 acc = {0.f, 0.f, 0.f, 0.f};
        #pragma unroll
        for (int ec = 0; ec < 2; ++ec) acc = MFMA(aK[ec], qB[mt][ec], acc);
        st[tt] = acc;
      }
      float mx = st[0][0];
      #pragma unroll
      for (int tt = 0; tt < 8; ++tt)
        #pragma unroll
        for (int rr = 0; rr < 4; ++rr) mx = fmaxf(mx, st[tt][rr]);
      mx = fmaxf(mx, __shfl_xor(mx, 16, 64));
      mx = fmaxf(mx, __shfl_xor(mx, 32, 64));
      float mn = fmaxf(m_st[mt], mx);
      float al = __expf(m_st[mt] - mn);
      m_st[mt] = mn;
      float sum = 0.f;
      #pragma unroll
      for (int tt = 0; tt < 8; ++tt)
        #pragma unroll
        for (int rr = 0; rr < 4; ++rr) {
          float pv = __expf(st[tt][rr] - mn);
          st[tt][rr] = pv;
          sum += pv;
        }
      sum += __shfl_xor(sum, 16, 64);
      sum += __shfl_xor(sum, 32, 64);
      l_st[mt] = l_st[mt] * al + sum;
      float af[4];
      #pragma unroll
      for (int rr = 0; rr < 4; ++rr) af[rr] = __shfl(al, 4 * g + rr, 64);
      #pragma unroll
      for (int e4 = 0; e4 < 4; ++e4)
        #pragma unroll
        for (int rr = 0; rr < 4; ++rr) O[mt][e4][rr] *= af[rr];
      #pragma unroll
      for (int u = 0; u < 4; ++u) {
        bf16x8 f;
        #pragma unroll
        for (int j = 0; j < 8; ++j) f[j] = (short)f2bf(st[2 * u + (j >> 2)][j & 3]);
        pA[u][mt] = f;
      }
    }
    #pragma unroll
    for (int u = 0; u < 4; ++u) {
      bf16x8 vB[4];
      #pragma unroll
      for (int e4 = 0; e4 < 4; ++e4)
        vB[e4] = ldfrag8(Vt + (16 * e4 + r16) * VP + 32 * u + cb8);
      #pragma unroll
      for (int mt = 0; mt < 2; ++mt)
        #pragma unroll
        for (int e4 = 0; e4 < 4; ++e4)
          O[mt][e4] = MFMA(pA[u][mt], vB[e4], O[mt][e4]);
    }
  }

  // ---- epilogue: normalize + store ----
  #pragma unroll
  for (int mt = 0; mt < 2; ++mt) {
    float inv[4];
    #pragma unroll
    for (int rr = 0; rr < 4; ++rr) inv[rr] = 1.0f / __shfl(l_st[mt], 4 * g + rr, 64);
    #pragma unroll
    for (int e4 = 0; e4 < 4; ++e4)
      #pragma unroll
      for (int rr = 0; rr < 4; ++rr)
        out[(size_t)(b * S_ + r0 + m0w + 16 * mt + 4 * g + rr) * D_ + h * DH_ + 16 * e4 + r16] =
            O[mt][e4][rr] * inv[rr];
  }
}

extern "C" void kernel_launch(void* const* d_in, const int* in_sizes, int n_in,
                              void* d_out, int out_size, void* d_ws, size_t ws_size,
                              hipStream_t stream) {
  const float* seq = (const float*)d_in[0];
  const float* Wq  = (const float*)d_in[1];
  const float* Wk  = (const float*)d_in[2];
  const float* Wv  = (const float*)d_in[3];
  const float* bq  = (const float*)d_in[4];
  const float* bk  = (const float*)d_in[5];
  const float* bv  = (const float*)d_in[6];
  float* outp = (float*)d_out;

  hipFuncSetAttribute((const void*)mhsa_mfma,
                      hipFuncAttributeMaxDynamicSharedMemorySize, SMEM_BYTES);
  dim3 grid(B_ * H_, 2);
  mhsa_mfma<<<grid, 512, SMEM_BYTES, stream>>>(seq, Wq, Wk, Wv, bq, bk, bv, outp);
}